// Round 9
// baseline (306.376 us; speedup 1.0000x reference)
//
#include <hip/hip_runtime.h>
#include <stdint.h>

#define BATCH 2
#define SEQ   4096
#define DM    2048
#define MT    (BATCH*SEQ)   /* 8192 rows total */
#define N1    (3*DM)        /* 6144 */
#define STRIP 16

typedef __attribute__((ext_vector_type(8))) __bf16 bf16x8;
typedef __attribute__((ext_vector_type(4))) float  f32x4;
typedef __attribute__((ext_vector_type(8))) unsigned short ushort8v;
typedef __attribute__((ext_vector_type(4))) unsigned short ushort4v;

__device__ inline unsigned short f2bf(float f) {
    uint32_t u = __float_as_uint(f);
    u += 0x7FFFu + ((u >> 16) & 1u);   // round-to-nearest-even
    return (unsigned short)(u >> 16);
}
__device__ inline float bf2f(unsigned short h) {
    return __uint_as_float(((uint32_t)h) << 16);
}

// ---------------- fp32 -> bf16 conversion (vectorized, grid-stride) --------
__global__ void cvt_f32_bf16(const float* __restrict__ src,
                             unsigned short* __restrict__ dst, int n) {
    int i = (blockIdx.x * blockDim.x + threadIdx.x) * 4;
    const int stride = gridDim.x * blockDim.x * 4;
    for (; i < n; i += stride) {
        const float4 v = *(const float4*)(src + i);
        ushort4v o;
        o[0] = f2bf(v.x); o[1] = f2bf(v.y); o[2] = f2bf(v.z); o[3] = f2bf(v.w);
        *(ushort4v*)(dst + i) = o;
    }
}

// ---------------- async global -> LDS (16B per lane) ------------------------
__device__ inline void async_copy16(const void* g, void* l) {
    __builtin_amdgcn_global_load_lds(
        (const __attribute__((address_space(1))) void*)g,
        (__attribute__((address_space(3))) void*)l,
        16, 0, 0);
}

// ============ 256x256 bf16 GEMM — R8 pipeline + interleaved MFMA issue ======
// C[M][N] = A[M][K] * B[N][K]^T.  BM=BN=256, BK=64, 512 threads (8 waves 2x4).
// R9 change (single variable vs R8): M8 issue order interleaved — all four
// kk=0 MFMAs (4 independent accumulators) issue BEFORE any kk=1 partner.
// Previously each acc was written twice back-to-back; MFMA is in-order issue
// per wave, so each dependent second-op stalled the wave ~L cycles and with
// only 2 waves/SIMD the matrix pipe sat idle.  Now each dependent op has
// >= 3 intervening independent MFMAs of issue distance.

#define MFMA_(d, a, b) d = __builtin_amdgcn_mfma_f32_16x16x32_bf16(a, b, d, 0, 0, 0)

// 8-MFMA cluster: A-half at acc rows K2,K2+1 x B-unit NH.
// Issue order: 4 independent kk=0 ops, then the 4 dependent kk=1 ops.
#define M8(K2, NH, AH, BQ) do { \
  MFMA_(acc[(K2)+0][(NH)*2+0], AH[0][0], BQ[0][0]); \
  MFMA_(acc[(K2)+0][(NH)*2+1], AH[0][0], BQ[1][0]); \
  MFMA_(acc[(K2)+1][(NH)*2+0], AH[1][0], BQ[0][0]); \
  MFMA_(acc[(K2)+1][(NH)*2+1], AH[1][0], BQ[1][0]); \
  MFMA_(acc[(K2)+0][(NH)*2+0], AH[0][1], BQ[0][1]); \
  MFMA_(acc[(K2)+0][(NH)*2+1], AH[0][1], BQ[1][1]); \
  MFMA_(acc[(K2)+1][(NH)*2+0], AH[1][1], BQ[0][1]); \
  MFMA_(acc[(K2)+1][(NH)*2+1], AH[1][1], BQ[1][1]); \
} while (0)

template <bool OUT_BF16>
__global__ __launch_bounds__(512)
void gemm256(const unsigned short* __restrict__ A,   // [M][K] bf16 bits
             const unsigned short* __restrict__ B,   // [N][K] bf16 bits
             void* __restrict__ Cout, int M, int N, int K) {
    __shared__ __attribute__((aligned(16))) char lds[131072];
    const int tid  = threadIdx.x;
    const int wave = tid >> 6;
    const int lane = tid & 63;
    const int wr = wave >> 2, wc = wave & 3;    // 2 x 4 wave grid
    const int l16 = lane & 15, lh = lane >> 4;
    const int NT = K >> 6;                      // K-tiles of 64 (NT even, >=2)

    // XCD-aware swizzle (grids here have nwg % 8 == 0 -> bijective)
    const int nx = gridDim.x;
    int flat = blockIdx.y * nx + blockIdx.x;
    const int cpx = (nx * gridDim.y) >> 3;
    flat = (flat & 7) * cpx + (flat >> 3);
    const int blockN = (flat % nx) << 8;
    const int blockM = (flat / nx) << 8;

    // ---- staging source addressing (pre-swizzled global col) ----
    const int swze = ((((lane & 7) << 4) ^ ((lane >> 3) << 4)) >> 1); // elems
    const int sr   = (wave << 3) + (lane >> 3);
    const unsigned short* Ab = A + (size_t)blockM * K;
    const unsigned short* Bb = B + (size_t)blockN * K;
    const size_t a00 = (size_t)(sr      ) * K + swze;
    const size_t a01 = (size_t)(sr +  64) * K + swze;
    const size_t a10 = (size_t)(sr + 128) * K + swze;
    const size_t a11 = (size_t)(sr + 192) * K + swze;
    const int bsr = ((wave >> 2) << 6) + ((wave & 3) << 3) + (lane >> 3);
    const size_t b00 = (size_t)(bsr      ) * K + swze;   // nh=0,d=0
    const size_t b01 = (size_t)(bsr + 128) * K + swze;   // nh=0,d=1
    const size_t b10 = (size_t)(bsr +  32) * K + swze;   // nh=1,d=0
    const size_t b11 = (size_t)(bsr + 160) * K + swze;   // nh=1,d=1
    const int ldsw = wave << 10;   // per-wave 1 KiB slice of each 8 KiB load

#define STG_A(BUF, U, K0) do { \
    async_copy16(Ab + a##U##0 + (K0), lds + (BUF) + (U)*16384 + ldsw); \
    async_copy16(Ab + a##U##1 + (K0), lds + (BUF) + (U)*16384 + 8192 + ldsw); } while (0)
#define STG_B(BUF, NH, K0) do { \
    async_copy16(Bb + b##NH##0 + (K0), lds + (BUF) + 32768 + (NH)*16384 + ldsw); \
    async_copy16(Bb + b##NH##1 + (K0), lds + (BUF) + 32768 + (NH)*16384 + 8192 + ldsw); } while (0)

    // ---- fragment read addressing (swizzled) ----
    const int rdswz = (l16 & 7) << 4;           // == (ldsrow&7)<<4 for all reads
    const int ac0 = ((lh << 4)      ) ^ rdswz;  // kk=0 col bytes
    const int ac1 = (64 + (lh << 4)) ^ rdswz;   // kk=1 col bytes
    const int aRB = wr * 16384 + l16 * 128;
    const int bRB = 32768 + (wc * 32 + l16) * 128;

#define LDA_(BUF, I, C) (*(const bf16x8*)(lds + (BUF) + aRB + (I)*2048 + (C)))
#define LDB_(BUF, J, C) (*(const bf16x8*)(lds + (BUF) + bRB + ((J)>>1)*16384 + ((J)&1)*2048 + (C)))

// read one A-half HI (frag rows 2HI, 2HI+1; both kk) into DST[2][2]
#define RD_A(DST, BUF, HI) do { \
    DST[0][0]=LDA_(BUF,2*(HI)  ,ac0); DST[0][1]=LDA_(BUF,2*(HI)  ,ac1); \
    DST[1][0]=LDA_(BUF,2*(HI)+1,ac0); DST[1][1]=LDA_(BUF,2*(HI)+1,ac1); } while (0)
// read one B-unit NH (n-frags 2NH, 2NH+1; both kk) into DST[2][2]
#define RD_B(DST, BUF, NH) do { \
    DST[0][0]=LDB_(BUF,2*(NH)  ,ac0); DST[0][1]=LDB_(BUF,2*(NH)  ,ac1); \
    DST[1][0]=LDB_(BUF,2*(NH)+1,ac0); DST[1][1]=LDB_(BUF,2*(NH)+1,ac1); } while (0)

    f32x4 acc[8][4] = {};
    bf16x8 afP[2][2], afQ[2][2], bq0[2][2], bq1[2][2];

    // ---- prologue: stage t0 -> buf0, t1 -> buf1; drain t0; pre-read ----
    STG_B(0, 0, 0); STG_B(0, 1, 0); STG_A(0, 0, 0); STG_A(0, 1, 0);
    STG_B(65536, 0, 64); STG_B(65536, 1, 64);
    STG_A(65536, 0, 64); STG_A(65536, 1, 64);
    asm volatile("s_waitcnt vmcnt(8)" ::: "memory");
    __builtin_amdgcn_s_barrier();
    RD_B(bq0, 0, 0);        // B-nh0(t0)
    RD_A(afP, 0, 0);        // A-half0(t0)

#define SP1 __builtin_amdgcn_s_setprio(1)
#define SP0 __builtin_amdgcn_s_setprio(0)

#define ITER(CUR, NXT, T) do { \
    /* sub0 (no bar): read bq1(t), h1(t); consume h0 x bq0 */ \
    RD_B(bq1, CUR, 1); \
    RD_A(afQ, CUR, 1); \
    SP1; M8(0, 0, afP, bq0); SP0; \
    /* sub1 [BAR]: STG B0(t+2) (bq0(t) LDS reads drained by sub0 M8 of all \
       waves before this barrier); consume h0 x bq1 */ \
    __builtin_amdgcn_s_barrier(); \
    if ((T) + 2 < NT) STG_B(CUR, 0, ((T)+2)*64); \
    SP1; M8(0, 1, afP, bq1); SP0; \
    /* sub2 (no bar): read h2(t) (afP reuse; anti-dep on sub1 M8); h1 x bq0 */ \
    RD_A(afP, CUR, 2); \
    SP1; M8(2, 0, afQ, bq0); SP0; \
    /* sub3 [BAR]: STG B1(t+2) (bq1 reads drained by sub1 M8); h1 x bq1 */ \
    __builtin_amdgcn_s_barrier(); \
    if ((T) + 2 < NT) STG_B(CUR, 1, ((T)+2)*64); \
    SP1; M8(2, 1, afQ, bq1); SP0; \
    /* sub4 (no bar): read h3(t); h2 x bq0 */ \
    RD_A(afQ, CUR, 3); \
    SP1; M8(4, 0, afP, bq0); SP0; \
    /* sub5 (no bar): h2 x bq1; per-wave vmcnt gate (t+1 loads) */ \
    SP1; M8(4, 1, afP, bq1); SP0; \
    if ((T) + 2 < NT)      { asm volatile("s_waitcnt vmcnt(4)" ::: "memory"); } \
    else if ((T) + 1 < NT) { asm volatile("s_waitcnt vmcnt(0)" ::: "memory"); } \
    /* sub6 [BAR]: all waves vmcnt-drained -> NXT tile fully in LDS; \
       read h0(t+1) from NXT; h3 x bq0 */ \
    __builtin_amdgcn_s_barrier(); \
    if ((T) + 1 < NT) RD_A(afP, NXT, 0); \
    SP1; M8(6, 0, afQ, bq0); SP0; \
    /* sub7 [BAR]: STG A0,A1(t+2) (h0..h3(t) reads drained by sub6 M8); \
       read bq0(t+1) from NXT; h3 x bq1 */ \
    __builtin_amdgcn_s_barrier(); \
    if ((T) + 2 < NT) { STG_A(CUR, 0, ((T)+2)*64); STG_A(CUR, 1, ((T)+2)*64); } \
    if ((T) + 1 < NT) RD_B(bq0, NXT, 0); \
    SP1; M8(6, 1, afQ, bq1); SP0; \
} while (0)

    for (int t = 0; t < NT; t += 2) {   // NT even (K=2048 -> 32)
        ITER(0, 65536, t);
        ITER(65536, 0, t + 1);
    }

    // ---- epilogue: C/D layout col=lane&15, row=(lane>>4)*4+reg ----
    const int orow = blockM + wr * 128 + (lh << 2);
    const int ocol = blockN + wc * 64 + l16;
    #pragma unroll
    for (int i = 0; i < 8; ++i) {
        #pragma unroll
        for (int j = 0; j < 4; ++j) {
            #pragma unroll
            for (int r = 0; r < 4; ++r) {
                const int row = orow + i * 16 + r;
                const int col = ocol + j * 16;
                if constexpr (OUT_BF16)
                    ((unsigned short*)Cout)[(size_t)row * N + col] = f2bf(acc[i][j][r]);
                else
                    ((float*)Cout)[(size_t)row * N + col] = acc[i][j][r];
            }
        }
    }
#undef ITER
#undef RD_A
#undef RD_B
#undef LDA_
#undef LDB_
#undef STG_A
#undef STG_B
}

// ---------------- fused u=Bg*Xg -> causal depthwise conv(K=3) -> Cg gate ----
__global__ void conv_gate_kernel(const unsigned short* __restrict__ BCx,
                                 const float* __restrict__ cw,   // [2048][3]
                                 unsigned short* __restrict__ gated) {
    const int tid = threadIdx.x;          // 256 threads: 8 channels each
    const int d0  = tid * 8;
    const int nstrips = SEQ / STRIP;      // 256
    const int b   = blockIdx.x / nstrips;
    const int s0  = (blockIdx.x % nstrips) * STRIP;

    float w0[8], w1c[8], w2c[8];
    #pragma unroll
    for (int c = 0; c < 8; ++c) {
        w0[c]  = cw[(d0 + c) * 3 + 0];
        w1c[c] = cw[(d0 + c) * 3 + 1];
        w2c[c] = cw[(d0 + c) * 3 + 2];
    }

    float um1[8], um2[8];
    if (s0 > 0) {
        const unsigned short* r2 = BCx + (size_t)(b * SEQ + s0 - 2) * N1;
        const unsigned short* r1 = BCx + (size_t)(b * SEQ + s0 - 1) * N1;
        ushort8v bg2 = *(const ushort8v*)(r2 + d0);
        ushort8v xg2 = *(const ushort8v*)(r2 + 2 * DM + d0);
        ushort8v bg1 = *(const ushort8v*)(r1 + d0);
        ushort8v xg1 = *(const ushort8v*)(r1 + 2 * DM + d0);
        #pragma unroll
        for (int c = 0; c < 8; ++c) {
            um2[c] = bf2f(bg2[c]) * bf2f(xg2[c]);
            um1[c] = bf2f(bg1[c]) * bf2f(xg1[c]);
        }
    } else {
        #pragma unroll
        for (int c = 0; c < 8; ++c) { um2[c] = 0.f; um1[c] = 0.f; }
    }

    for (int s = s0; s < s0 + STRIP; ++s) {
        const size_t m = (size_t)b * SEQ + s;
        const unsigned short* rp = BCx + m * N1;
        ushort8v bg = *(const ushort8v*)(rp + d0);
        ushort8v cg = *(const ushort8v*)(rp + DM + d0);
        ushort8v xg = *(const ushort8v*)(rp + 2 * DM + d0);
        ushort8v og;
        #pragma unroll
        for (int c = 0; c < 8; ++c) {
            const float u    = bf2f(bg[c]) * bf2f(xg[c]);
            const float conv = w0[c] * um2[c] + w1c[c] * um1[c] + w2c[c] * u;
            const float g    = bf2f(cg[c]) * conv;
            um2[c] = um1[c];
            um1[c] = u;
            og[c]  = f2bf(g);
        }
        *(ushort8v*)(gated + m * DM + d0) = og;
    }
}

// ---------------- launch ----------------------------------------------------
extern "C" void kernel_launch(void* const* d_in, const int* in_sizes, int n_in,
                              void* d_out, int out_size, void* d_ws, size_t ws_size,
                              hipStream_t stream) {
    const float* x   = (const float*)d_in[0];   // [2][4096][2048]
    const float* w1  = (const float*)d_in[1];   // [6144][2048]
    const float* w2  = (const float*)d_in[2];   // [2048][2048]
    const float* cw  = (const float*)d_in[3];   // [2048][1][3]
    float* out = (float*)d_out;                 // [2][4096][2048] fp32

    char* ws = (char*)d_ws;
    unsigned short* x_bf   = (unsigned short*)ws;
    unsigned short* w1_bf  = x_bf  + (size_t)MT * DM;
    unsigned short* w2_bf  = w1_bf + (size_t)N1 * DM;
    unsigned short* bcx_bf = w2_bf + (size_t)DM * DM;
    unsigned short* g_bf   = bcx_bf + (size_t)MT * N1;

    cvt_f32_bf16<<<2048, 256, 0, stream>>>(x,  x_bf,  MT * DM);
    cvt_f32_bf16<<<1024, 256, 0, stream>>>(w1, w1_bf, N1 * DM);
    cvt_f32_bf16<<<512,  256, 0, stream>>>(w2, w2_bf, DM * DM);

    // GEMM1: BCx[8192][6144] = x_bf @ w1_bf^T   (grid 24x32 = 768 wgs, %8==0)
    gemm256<true><<<dim3(N1 / 256, MT / 256), 512, 0, stream>>>(
        x_bf, w1_bf, bcx_bf, MT, N1, DM);

    // fused elementwise + causal depthwise conv + gate
    conv_gate_kernel<<<BATCH * (SEQ / STRIP), 256, 0, stream>>>(bcx_bf, cw, g_bf);

    // GEMM2: out[8192][2048] = g_bf @ w2_bf^T   (grid 8x32 = 256 wgs, %8==0)
    gemm256<false><<<dim3(DM / 256, MT / 256), 512, 0, stream>>>(
        g_bf, w2_bf, out, MT, DM, DM);
}

// Round 10
// 299.372 us; speedup vs baseline: 1.0234x; 1.0234x over previous
//
#include <hip/hip_runtime.h>
#include <stdint.h>

#define BATCH 2
#define SEQ   4096
#define DM    2048
#define MT    (BATCH*SEQ)   /* 8192 rows total */
#define N1    (3*DM)        /* 6144 */
#define STRIP 16

typedef __attribute__((ext_vector_type(8))) __bf16 bf16x8;
typedef __attribute__((ext_vector_type(4))) float  f32x4;
typedef __attribute__((ext_vector_type(8))) unsigned short ushort8v;
typedef __attribute__((ext_vector_type(4))) unsigned short ushort4v;

__device__ inline unsigned short f2bf(float f) {
    uint32_t u = __float_as_uint(f);
    u += 0x7FFFu + ((u >> 16) & 1u);   // round-to-nearest-even
    return (unsigned short)(u >> 16);
}
__device__ inline float bf2f(unsigned short h) {
    return __uint_as_float(((uint32_t)h) << 16);
}

// -------- fused fp32 -> bf16 conversion for x, w1, w2 (one launch) ---------
__global__ void cvt_all_bf16(const float* __restrict__ s0, int n0,
                             const float* __restrict__ s1, int n1,
                             const float* __restrict__ s2, int n2,
                             unsigned short* __restrict__ dst) {
    const int total = (n0 + n1 + n2) >> 2;
    const int stride = gridDim.x * blockDim.x;
    for (int q = blockIdx.x * blockDim.x + threadIdx.x; q < total; q += stride) {
        const int i = q << 2;
        const float* src;
        int off;
        if (i < n0)            { src = s0; off = i; }
        else if (i < n0 + n1)  { src = s1; off = i - n0; }
        else                   { src = s2; off = i - n0 - n1; }
        const float4 v = *(const float4*)(src + off);
        ushort4v o;
        o[0] = f2bf(v.x); o[1] = f2bf(v.y); o[2] = f2bf(v.z); o[3] = f2bf(v.w);
        *(ushort4v*)(dst + i) = o;
    }
}

// ---------------- async global -> LDS (16B per lane) ------------------------
__device__ inline void async_copy16(const void* g, void* l) {
    __builtin_amdgcn_global_load_lds(
        (const __attribute__((address_space(1))) void*)g,
        (__attribute__((address_space(3))) void*)l,
        16, 0, 0);
}

// ============ 256x256 bf16 GEMM — R8 pipeline, 256-VGPR budget ==============
// C[M][N] = A[M][K] * B[N][K]^T.  BM=BN=256, BK=64, 512 threads (8 waves 2x4).
// R10 vs R8/R9:
//  (1) __launch_bounds__(512, 1): hipcc's 2nd arg is min BLOCKS/CU (R5
//      evidence: arg=2 pinned VGPR to 128 + spilled).  LDS already caps at
//      1 block/CU = 2 waves/SIMD, so the honest budget is 256 VGPR/wave —
//      gives the scheduler headroom to hoist ds_reads across MFMA clusters.
//  (2) A staging split: A-unit0 at sub4 (new barrier; its frag reads h0/h1
//      complete by sub3's M8), A-unit1 at sub7.  VMEM = 2+2+2+2 loads/K-tile.
//  (3) vmcnt gate at sub5: steady = 6 (B0,B1,A0 of t+2 outstanding).
#define MFMA_(d, a, b) d = __builtin_amdgcn_mfma_f32_16x16x32_bf16(a, b, d, 0, 0, 0)

// 8-MFMA cluster: A-half at acc rows K2,K2+1 x B-unit NH (kk-interleaved).
#define M8(K2, NH, AH, BQ) do { \
  MFMA_(acc[(K2)+0][(NH)*2+0], AH[0][0], BQ[0][0]); \
  MFMA_(acc[(K2)+0][(NH)*2+1], AH[0][0], BQ[1][0]); \
  MFMA_(acc[(K2)+1][(NH)*2+0], AH[1][0], BQ[0][0]); \
  MFMA_(acc[(K2)+1][(NH)*2+1], AH[1][0], BQ[1][0]); \
  MFMA_(acc[(K2)+0][(NH)*2+0], AH[0][1], BQ[0][1]); \
  MFMA_(acc[(K2)+0][(NH)*2+1], AH[0][1], BQ[1][1]); \
  MFMA_(acc[(K2)+1][(NH)*2+0], AH[1][1], BQ[0][1]); \
  MFMA_(acc[(K2)+1][(NH)*2+1], AH[1][1], BQ[1][1]); \
} while (0)

template <bool OUT_BF16>
__global__ __launch_bounds__(512, 1)
void gemm256(const unsigned short* __restrict__ A,   // [M][K] bf16 bits
             const unsigned short* __restrict__ B,   // [N][K] bf16 bits
             void* __restrict__ Cout, int M, int N, int K) {
    __shared__ __attribute__((aligned(16))) char lds[131072];
    const int tid  = threadIdx.x;
    const int wave = tid >> 6;
    const int lane = tid & 63;
    const int wr = wave >> 2, wc = wave & 3;    // 2 x 4 wave grid
    const int l16 = lane & 15, lh = lane >> 4;
    const int NT = K >> 6;                      // K-tiles of 64 (NT even, >=2)

    // XCD-aware swizzle (grids here have nwg % 8 == 0 -> bijective)
    const int nx = gridDim.x;
    int flat = blockIdx.y * nx + blockIdx.x;
    const int cpx = (nx * gridDim.y) >> 3;
    flat = (flat & 7) * cpx + (flat >> 3);
    const int blockN = (flat % nx) << 8;
    const int blockM = (flat / nx) << 8;

    // ---- staging source addressing (pre-swizzled global col) ----
    const int swze = ((((lane & 7) << 4) ^ ((lane >> 3) << 4)) >> 1); // elems
    const int sr   = (wave << 3) + (lane >> 3);
    const unsigned short* Ab = A + (size_t)blockM * K;
    const unsigned short* Bb = B + (size_t)blockN * K;
    const size_t a00 = (size_t)(sr      ) * K + swze;
    const size_t a01 = (size_t)(sr +  64) * K + swze;
    const size_t a10 = (size_t)(sr + 128) * K + swze;
    const size_t a11 = (size_t)(sr + 192) * K + swze;
    const int bsr = ((wave >> 2) << 6) + ((wave & 3) << 3) + (lane >> 3);
    const size_t b00 = (size_t)(bsr      ) * K + swze;   // nh=0,d=0
    const size_t b01 = (size_t)(bsr + 128) * K + swze;   // nh=0,d=1
    const size_t b10 = (size_t)(bsr +  32) * K + swze;   // nh=1,d=0
    const size_t b11 = (size_t)(bsr + 160) * K + swze;   // nh=1,d=1
    const int ldsw = wave << 10;   // per-wave 1 KiB slice of each 8 KiB load

#define STG_A(BUF, U, K0) do { \
    async_copy16(Ab + a##U##0 + (K0), lds + (BUF) + (U)*16384 + ldsw); \
    async_copy16(Ab + a##U##1 + (K0), lds + (BUF) + (U)*16384 + 8192 + ldsw); } while (0)
#define STG_B(BUF, NH, K0) do { \
    async_copy16(Bb + b##NH##0 + (K0), lds + (BUF) + 32768 + (NH)*16384 + ldsw); \
    async_copy16(Bb + b##NH##1 + (K0), lds + (BUF) + 32768 + (NH)*16384 + 8192 + ldsw); } while (0)

    // ---- fragment read addressing (swizzled) ----
    const int rdswz = (l16 & 7) << 4;           // == (ldsrow&7)<<4 for all reads
    const int ac0 = ((lh << 4)      ) ^ rdswz;  // kk=0 col bytes
    const int ac1 = (64 + (lh << 4)) ^ rdswz;   // kk=1 col bytes
    const int aRB = wr * 16384 + l16 * 128;
    const int bRB = 32768 + (wc * 32 + l16) * 128;

#define LDA_(BUF, I, C) (*(const bf16x8*)(lds + (BUF) + aRB + (I)*2048 + (C)))
#define LDB_(BUF, J, C) (*(const bf16x8*)(lds + (BUF) + bRB + ((J)>>1)*16384 + ((J)&1)*2048 + (C)))

// read one A-half HI (frag rows 2HI, 2HI+1; both kk) into DST[2][2]
#define RD_A(DST, BUF, HI) do { \
    DST[0][0]=LDA_(BUF,2*(HI)  ,ac0); DST[0][1]=LDA_(BUF,2*(HI)  ,ac1); \
    DST[1][0]=LDA_(BUF,2*(HI)+1,ac0); DST[1][1]=LDA_(BUF,2*(HI)+1,ac1); } while (0)
// read one B-unit NH (n-frags 2NH, 2NH+1; both kk) into DST[2][2]
#define RD_B(DST, BUF, NH) do { \
    DST[0][0]=LDB_(BUF,2*(NH)  ,ac0); DST[0][1]=LDB_(BUF,2*(NH)  ,ac1); \
    DST[1][0]=LDB_(BUF,2*(NH)+1,ac0); DST[1][1]=LDB_(BUF,2*(NH)+1,ac1); } while (0)

    f32x4 acc[8][4] = {};
    bf16x8 afP[2][2], afQ[2][2], bq0[2][2], bq1[2][2];

    // ---- prologue: stage t0 -> buf0, t1 -> buf1; drain t0; pre-read ----
    STG_B(0, 0, 0); STG_B(0, 1, 0); STG_A(0, 0, 0); STG_A(0, 1, 0);
    STG_B(65536, 0, 64); STG_B(65536, 1, 64);
    STG_A(65536, 0, 64); STG_A(65536, 1, 64);
    asm volatile("s_waitcnt vmcnt(8)" ::: "memory");
    __builtin_amdgcn_s_barrier();
    RD_B(bq0, 0, 0);        // B-nh0(t0)
    RD_A(afP, 0, 0);        // A-half0(t0)

#define SP1 __builtin_amdgcn_s_setprio(1)
#define SP0 __builtin_amdgcn_s_setprio(0)

#define ITER(CUR, NXT, T) do { \
    /* sub0 (no bar): read bq1(t), h1(t); consume h0 x bq0 */ \
    RD_B(bq1, CUR, 1); \
    RD_A(afQ, CUR, 1); \
    SP1; M8(0, 0, afP, bq0); SP0; \
    /* sub1 [BAR]: STG B0(t+2) (bq0(t) reads drained by sub0 M8 everywhere); \
       consume h0 x bq1 */ \
    __builtin_amdgcn_s_barrier(); \
    if ((T) + 2 < NT) STG_B(CUR, 0, ((T)+2)*64); \
    SP1; M8(0, 1, afP, bq1); SP0; \
    /* sub2 (no bar): read h2(t); h1 x bq0 */ \
    RD_A(afP, CUR, 2); \
    SP1; M8(2, 0, afQ, bq0); SP0; \
    /* sub3 [BAR]: STG B1(t+2) (bq1 reads drained by sub1 M8); h1 x bq1 */ \
    __builtin_amdgcn_s_barrier(); \
    if ((T) + 2 < NT) STG_B(CUR, 1, ((T)+2)*64); \
    SP1; M8(2, 1, afQ, bq1); SP0; \
    /* sub4 [BAR]: STG A0(t+2) (h0/h1 reads drained by sub2/3 M8); \
       read h3(t); h2 x bq0 */ \
    __builtin_amdgcn_s_barrier(); \
    if ((T) + 2 < NT) STG_A(CUR, 0, ((T)+2)*64); \
    RD_A(afQ, CUR, 3); \
    SP1; M8(4, 0, afP, bq0); SP0; \
    /* sub5 (no bar): h2 x bq1; per-wave vmcnt gate: leave the 6 t+2 loads \
       (B0,B1,A0) outstanding -> all t+1 loads proven landed */ \
    SP1; M8(4, 1, afP, bq1); SP0; \
    if ((T) + 2 < NT)      { asm volatile("s_waitcnt vmcnt(6)" ::: "memory"); } \
    else if ((T) + 1 < NT) { asm volatile("s_waitcnt vmcnt(0)" ::: "memory"); } \
    /* sub6 [BAR]: all waves vmcnt-drained -> NXT tile fully in LDS; \
       read h0(t+1) from NXT; h3 x bq0 */ \
    __builtin_amdgcn_s_barrier(); \
    if ((T) + 1 < NT) RD_A(afP, NXT, 0); \
    SP1; M8(6, 0, afQ, bq0); SP0; \
    /* sub7 [BAR]: STG A1(t+2) (h2/h3 reads drained by sub4-6 M8); \
       read bq0(t+1) from NXT; h3 x bq1 */ \
    __builtin_amdgcn_s_barrier(); \
    if ((T) + 2 < NT) STG_A(CUR, 1, ((T)+2)*64); \
    if ((T) + 1 < NT) RD_B(bq0, NXT, 0); \
    SP1; M8(6, 1, afQ, bq1); SP0; \
} while (0)

    for (int t = 0; t < NT; t += 2) {   // NT even (K=2048 -> 32)
        ITER(0, 65536, t);
        ITER(65536, 0, t + 1);
    }

    // ---- epilogue: C/D layout col=lane&15, row=(lane>>4)*4+reg ----
    const int orow = blockM + wr * 128 + (lh << 2);
    const int ocol = blockN + wc * 64 + l16;
    #pragma unroll
    for (int i = 0; i < 8; ++i) {
        #pragma unroll
        for (int j = 0; j < 4; ++j) {
            #pragma unroll
            for (int r = 0; r < 4; ++r) {
                const int row = orow + i * 16 + r;
                const int col = ocol + j * 16;
                if constexpr (OUT_BF16)
                    ((unsigned short*)Cout)[(size_t)row * N + col] = f2bf(acc[i][j][r]);
                else
                    ((float*)Cout)[(size_t)row * N + col] = acc[i][j][r];
            }
        }
    }
#undef ITER
#undef RD_A
#undef RD_B
#undef LDA_
#undef LDB_
#undef STG_A
#undef STG_B
}

// ---------------- fused u=Bg*Xg -> causal depthwise conv(K=3) -> Cg gate ----
__global__ void conv_gate_kernel(const unsigned short* __restrict__ BCx,
                                 const float* __restrict__ cw,   // [2048][3]
                                 unsigned short* __restrict__ gated) {
    const int tid = threadIdx.x;          // 256 threads: 8 channels each
    const int d0  = tid * 8;
    const int nstrips = SEQ / STRIP;      // 256
    const int b   = blockIdx.x / nstrips;
    const int s0  = (blockIdx.x % nstrips) * STRIP;

    float w0[8], w1c[8], w2c[8];
    #pragma unroll
    for (int c = 0; c < 8; ++c) {
        w0[c]  = cw[(d0 + c) * 3 + 0];
        w1c[c] = cw[(d0 + c) * 3 + 1];
        w2c[c] = cw[(d0 + c) * 3 + 2];
    }

    float um1[8], um2[8];
    if (s0 > 0) {
        const unsigned short* r2 = BCx + (size_t)(b * SEQ + s0 - 2) * N1;
        const unsigned short* r1 = BCx + (size_t)(b * SEQ + s0 - 1) * N1;
        ushort8v bg2 = *(const ushort8v*)(r2 + d0);
        ushort8v xg2 = *(const ushort8v*)(r2 + 2 * DM + d0);
        ushort8v bg1 = *(const ushort8v*)(r1 + d0);
        ushort8v xg1 = *(const ushort8v*)(r1 + 2 * DM + d0);
        #pragma unroll
        for (int c = 0; c < 8; ++c) {
            um2[c] = bf2f(bg2[c]) * bf2f(xg2[c]);
            um1[c] = bf2f(bg1[c]) * bf2f(xg1[c]);
        }
    } else {
        #pragma unroll
        for (int c = 0; c < 8; ++c) { um2[c] = 0.f; um1[c] = 0.f; }
    }

    for (int s = s0; s < s0 + STRIP; ++s) {
        const size_t m = (size_t)b * SEQ + s;
        const unsigned short* rp = BCx + m * N1;
        ushort8v bg = *(const ushort8v*)(rp + d0);
        ushort8v cg = *(const ushort8v*)(rp + DM + d0);
        ushort8v xg = *(const ushort8v*)(rp + 2 * DM + d0);
        ushort8v og;
        #pragma unroll
        for (int c = 0; c < 8; ++c) {
            const float u    = bf2f(bg[c]) * bf2f(xg[c]);
            const float conv = w0[c] * um2[c] + w1c[c] * um1[c] + w2c[c] * u;
            const float g    = bf2f(cg[c]) * conv;
            um2[c] = um1[c];
            um1[c] = u;
            og[c]  = f2bf(g);
        }
        *(ushort8v*)(gated + m * DM + d0) = og;
    }
}

// ---------------- launch ----------------------------------------------------
extern "C" void kernel_launch(void* const* d_in, const int* in_sizes, int n_in,
                              void* d_out, int out_size, void* d_ws, size_t ws_size,
                              hipStream_t stream) {
    const float* x   = (const float*)d_in[0];   // [2][4096][2048]
    const float* w1  = (const float*)d_in[1];   // [6144][2048]
    const float* w2  = (const float*)d_in[2];   // [2048][2048]
    const float* cw  = (const float*)d_in[3];   // [2048][1][3]
    float* out = (float*)d_out;                 // [2][4096][2048] fp32

    char* ws = (char*)d_ws;
    unsigned short* x_bf   = (unsigned short*)ws;
    unsigned short* w1_bf  = x_bf  + (size_t)MT * DM;      // contiguous with x_bf
    unsigned short* w2_bf  = w1_bf + (size_t)N1 * DM;      // contiguous with w1_bf
    unsigned short* bcx_bf = w2_bf + (size_t)DM * DM;
    unsigned short* g_bf   = bcx_bf + (size_t)MT * N1;

    // one fused conversion launch over the contiguous bf16 region
    cvt_all_bf16<<<3072, 256, 0, stream>>>(x,  MT * DM,
                                           w1, N1 * DM,
                                           w2, DM * DM, x_bf);

    // GEMM1: BCx[8192][6144] = x_bf @ w1_bf^T   (grid 24x32 = 768 wgs, %8==0)
    gemm256<true><<<dim3(N1 / 256, MT / 256), 512, 0, stream>>>(
        x_bf, w1_bf, bcx_bf, MT, N1, DM);

    // fused elementwise + causal depthwise conv + gate
    conv_gate_kernel<<<BATCH * (SEQ / STRIP), 256, 0, stream>>>(bcx_bf, cw, g_bf);

    // GEMM2: out[8192][2048] = g_bf @ w2_bf^T   (grid 8x32 = 256 wgs, %8==0)
    gemm256<false><<<dim3(DM / 256, MT / 256), 512, 0, stream>>>(
        g_bf, w2_bf, out, MT, DM, DM);
}